// Round 15
// baseline (581.094 us; speedup 1.0000x reference)
//
#include <hip/hip_runtime.h>
#include <hip/hip_bf16.h>

typedef __attribute__((ext_vector_type(8))) short short8;
typedef __attribute__((ext_vector_type(4))) float floatx4;

struct ushort4v { unsigned short x, y, z, w; };

static __device__ __forceinline__ unsigned short f2bf(float f) {
    __hip_bfloat16 h = __float2bfloat16(f);
    return *reinterpret_cast<unsigned short*>(&h);
}

static __device__ __forceinline__ float bf2f(unsigned short u) {
    unsigned int v = ((unsigned int)u) << 16;
    return *reinterpret_cast<float*>(&v);
}

#define ASYNC_COPY16(gsrc, ldst)                                                            \
    __builtin_amdgcn_global_load_lds((const __attribute__((address_space(1))) void*)(gsrc), \
                                     (__attribute__((address_space(3))) void*)(ldst), 16, 0, 0)

static __device__ __forceinline__ void block_barrier() {
    asm volatile("" ::: "memory");
    __builtin_amdgcn_s_barrier();
    asm volatile("" ::: "memory");
}

// ---------------------------------------------------------------------------
// One prep launch, grid-partitioned into 3 independent jobs:
//   blocks [0,8192)        : fp32 -> bf16 convert of x (1KB per block)
//   blocks [8192,11264)    : weight transpose+convert (32x32 tile each)
//   blocks [11264,11296)   : mask expand (encoding re-derived per block)
// ---------------------------------------------------------------------------
__global__ __launch_bounds__(256) void prep_kernel(const float* __restrict__ x,
                                                   unsigned short* __restrict__ xb,
                                                   const float* __restrict__ w0,
                                                   const float* __restrict__ w1,
                                                   const float* __restrict__ w2,
                                                   unsigned short* __restrict__ wT,
                                                   const unsigned char* __restrict__ mask,
                                                   float* __restrict__ keep, int nMask) {
    __shared__ float t[32][33];
    __shared__ int s_or;
    const int b = blockIdx.x;
    const int tid = threadIdx.x;

    if (b < 8192) {                       // convert: 1024 fp32 per block
        long i = (long)b * 256 + tid;
        float4 v = ((const float4*)x)[i];
        ushort4v o;
        o.x = f2bf(v.x); o.y = f2bf(v.y); o.z = f2bf(v.z); o.w = f2bf(v.w);
        ((ushort4v*)xb)[i] = o;
    } else if (b < 11264) {               // transpose_w: 32x32 tile
        int idx = b - 8192;
        int z = idx >> 10, rem = idx & 1023;
        int bx = rem & 31, by = rem >> 5;
        const float* w = z == 0 ? w0 : (z == 1 ? w1 : w2);
        unsigned short* o = wT + (long)z * 1024 * 1024;
        int c0 = bx * 32, r0 = by * 32;
        int tx = tid & 31, ty = tid >> 5;  // 32 x 8
        for (int i = ty; i < 32; i += 8)
            t[i][tx] = w[(long)(r0 + i) * 1024 + c0 + tx];
        __syncthreads();
        for (int i = ty; i < 32; i += 8)
            o[(long)(c0 + i) * 1024 + r0 + tx] = f2bf(t[tx][i]);
    } else {                              // mask expand
        if (tid == 0) s_or = 0;
        __syncthreads();
        int acc = 0;
        for (int i = tid; i < 8192; i += 256)
            if (i & 3) acc |= mask[i];
        atomicOr(&s_or, acc);
        __syncthreads();
        const bool u8enc = (s_or != 0);
        int i = (b - 11264) * 256 + tid;
        if (i < nMask) {
            bool on = u8enc ? (mask[i] != 0) : (((const int*)mask)[i] != 0);
            keep[i] = on ? 1.0f : 0.0f;
        }
    }
}

// ---------------------------------------------------------------------------
// Ring GEMM: C[M,N] = A[M,K] * BT[N,K]^T  (bf16 in, fp32 accum)
// 128x256 tile, BK=32, 8 waves, one barrier per K-step, 64B-row swizzle.
// DEPTH=3: 72KB ring, counted vmcnt(3)/(0), 2 blocks/CU (scores, PV).
// DEPTH=2: 48KB ring, vmcnt(0)/step (loads issued a full step earlier),
//          3 blocks/CU -> QKV's 768-block grid = exactly one round.
// EPI 0: QKV — z<2 bf16 C; z==2 V TRANSPOSED to vt via LDS (two 128-d-half
//        passes to fit the 48KB ring; batch-decomposed flattened M).
// EPI 1: bf16 exp(acc*scale*keep[row]).   EPI 2: fp32 acc*invsum[row].
// ---------------------------------------------------------------------------
template <int EPI, int DEPTH>
static __device__ __forceinline__ void gemm8_body(const unsigned short* __restrict__ A,
                                                  const unsigned short* __restrict__ B,
                                                  void* __restrict__ Cv,
                                                  unsigned short* __restrict__ vt,
                                                  const float* __restrict__ aux,
                                                  int K, int lda, int ldb, int ldc,
                                                  long sA, long sB, long sC, long sAux,
                                                  float scale) {
    constexpr int TILE = (128 + 256) * 32 * 2;  // 24576 B per K-tile (A+B)
    __shared__ char sm[DEPTH * TILE];

    const int tid = threadIdx.x;
    const int wid = tid >> 6, lane = tid & 63;
    const int wm  = wid >> 2, wn = wid & 3;       // 2 x 4 wave grid
    const int fr  = lane & 15, fk = lane >> 4;
    const long m0 = (long)blockIdx.x * 128;
    const long n0 = (long)blockIdx.y * 256;
    const unsigned short* Ab = A + (long)blockIdx.z * sA + m0 * lda;
    const unsigned short* Bb = B + (long)blockIdx.z * sB + n0 * ldb;
    const int NT = K >> 5;

    floatx4 acc[4][4] = {};

    auto stage = [&](int kt, int buf) {
        char* dA = sm + buf * TILE;
        char* dB = dA + 128 * 64;                 // A part = 8192 B
        const int kb = kt << 5;
        {
            int lam = tid * 16;
            int lg  = lam ^ (((lam >> 7) & 3) << 4);
            ASYNC_COPY16(Ab + (long)(lg >> 6) * lda + kb + ((lg & 63) >> 1), dA + lam);
        }
#pragma unroll
        for (int i = 0; i < 2; i++) {
            int lam = i * 8192 + tid * 16;
            int lg  = lam ^ (((lam >> 7) & 3) << 4);
            ASYNC_COPY16(Bb + (long)(lg >> 6) * ldb + kb + ((lg & 63) >> 1), dB + lam);
        }
    };

    stage(0, 0);
    if (DEPTH == 3) stage(1, 1);

    int cur = 0;
    for (int t = 0; t < NT; t++) {
        if (DEPTH == 3) {
            if (t + 1 < NT) asm volatile("s_waitcnt vmcnt(3)" ::: "memory");
            else            asm volatile("s_waitcnt vmcnt(0)" ::: "memory");
        } else {
            asm volatile("s_waitcnt vmcnt(0)" ::: "memory");
        }
        block_barrier();   // all waves' reads of tile t-1 returned (lgkm chain)

        const char* bA = sm + cur * TILE;
        const char* bB = bA + 128 * 64;
        short8 af[4], bf[4];
#pragma unroll
        for (int mi = 0; mi < 4; mi++) {
            int row = wm * 64 + mi * 16 + fr;
            int c   = (fk * 16) ^ (((row >> 1) & 3) << 4);
            af[mi] = *(const short8*)(bA + row * 64 + c);
        }
#pragma unroll
        for (int ni = 0; ni < 4; ni++) {
            int row = wn * 64 + ni * 16 + fr;
            int c   = (fk * 16) ^ (((row >> 1) & 3) << 4);
            bf[ni] = *(const short8*)(bB + row * 64 + c);
        }
        if (DEPTH == 3) {
            if (t + 2 < NT) stage(t + 2, (cur + 2) % 3);
        } else {
            if (t + 1 < NT) stage(t + 1, cur ^ 1);
        }

        __builtin_amdgcn_s_setprio(1);
#pragma unroll
        for (int mi = 0; mi < 4; mi++)
#pragma unroll
            for (int ni = 0; ni < 4; ni++)
                acc[mi][ni] = __builtin_amdgcn_mfma_f32_16x16x32_bf16(af[mi], bf[ni], acc[mi][ni], 0, 0, 0);
        __builtin_amdgcn_s_setprio(0);
        cur = (DEPTH == 3) ? ((cur == 2) ? 0 : cur + 1) : (cur ^ 1);
    }

    const int crow = (lane >> 4) * 4;
    const int ccol = lane & 15;

    if (EPI == 0 && blockIdx.z == 2) {
        // V: emit TRANSPOSED via LDS in two 128-d-half passes (fits 48KB ring).
        unsigned short* T = (unsigned short*)sm;
        constexpr int LDT = 132;                 // pad breaks bank conflicts
        const long bb   = m0 >> 11;              // batch = m0 / 2048
        const long sloc = m0 & 2047;             // s offset within batch
        unsigned short* vb = vt + bb * (1024L * 2048) + sloc;
#pragma unroll
        for (int dh = 0; dh < 2; dh++) {
            block_barrier();                     // ring reads / prior pass done
            if ((wn >> 1) == dh) {               // waves owning this d-half
#pragma unroll
                for (int mi = 0; mi < 4; mi++)
#pragma unroll
                    for (int j = 0; j < 4; j++) {
                        int rl = wm * 64 + mi * 16 + crow + j;        // s-local
#pragma unroll
                        for (int ni = 0; ni < 4; ni++) {
                            int clh = (wn & 1) * 64 + ni * 16 + ccol; // d within half
                            T[clh * LDT + rl] = f2bf(acc[mi][ni][j]);
                        }
                    }
            }
            block_barrier();
            // store this 128-d x 128-s half: 2048 chunks of 16B over 512 thr
#pragma unroll
            for (int p = 0; p < 4; p++) {
                int chunk = p * 512 + tid;
                int d  = chunk >> 4;
                int s0 = (chunk & 15) * 8;
                short8 v = *(const short8*)&T[d * LDT + s0];
                *(short8*)(vb + (n0 + dh * 128 + d) * 2048 + s0) = v;
            }
        }
        return;
    }

#pragma unroll
    for (int mi = 0; mi < 4; mi++) {
#pragma unroll
        for (int j = 0; j < 4; j++) {
            long r = m0 + wm * 64 + mi * 16 + crow + j;
            float rowf = 0.0f;
            if (EPI == 1) rowf = scale * aux[(long)blockIdx.z * sAux + r];  // scale*keep
            if (EPI == 2) rowf = aux[(long)blockIdx.z * sAux + r];          // invsum
#pragma unroll
            for (int ni = 0; ni < 4; ni++) {
                long c = n0 + wn * 64 + ni * 16 + ccol;
                float v = acc[mi][ni][j];
                if (EPI == 0) {
                    ((unsigned short*)Cv)[(long)blockIdx.z * sC + r * ldc + c] = f2bf(v);
                } else if (EPI == 1) {
                    ((unsigned short*)Cv)[(long)blockIdx.z * sC + r * ldc + c] = f2bf(__expf(v * rowf));
                } else {
                    ((float*)Cv)[(long)blockIdx.z * sC + r * ldc + c] = v * rowf;
                }
            }
        }
    }
}

__global__ __launch_bounds__(512, 6) void gemm8_qkv(const unsigned short* __restrict__ A,
                                                    const unsigned short* __restrict__ B,
                                                    void* __restrict__ Cv,
                                                    unsigned short* __restrict__ vt,
                                                    int K, int lda, int ldb, int ldc,
                                                    long sA, long sB, long sC) {
    gemm8_body<0, 2>(A, B, Cv, vt, nullptr, K, lda, ldb, ldc, sA, sB, sC, 0L, 1.0f);
}

__global__ __launch_bounds__(512, 4) void gemm8_scores(const unsigned short* __restrict__ A,
                                                       const unsigned short* __restrict__ B,
                                                       void* __restrict__ Cv,
                                                       const float* __restrict__ keep,
                                                       int K, int lda, int ldb, int ldc,
                                                       long sA, long sB, long sC, long sAux,
                                                       float scale) {
    gemm8_body<1, 3>(A, B, Cv, nullptr, keep, K, lda, ldb, ldc, sA, sB, sC, sAux, scale);
}

__global__ __launch_bounds__(512, 4) void gemm8_pv(const unsigned short* __restrict__ A,
                                                   const unsigned short* __restrict__ B,
                                                   void* __restrict__ Cv,
                                                   const float* __restrict__ invsum,
                                                   int K, int lda, int ldb, int ldc,
                                                   long sA, long sB, long sC, long sAux) {
    gemm8_body<2, 3>(A, B, Cv, nullptr, invsum, K, lda, ldb, ldc, sA, sB, sC, sAux, 1.0f);
}

// ---------------------------------------------------------------------------
__global__ __launch_bounds__(256) void rowsum_inv(const unsigned short* __restrict__ P,
                                                  float* __restrict__ inv, long strideP) {
    const int tid = threadIdx.x;
    const long row = blockIdx.x;
    short8 v = ((const short8*)(P + row * strideP))[tid];
    float s = 0.0f;
#pragma unroll
    for (int i = 0; i < 8; i++) s += bf2f((unsigned short)v[i]);
#pragma unroll
    for (int i = 1; i < 64; i <<= 1) s += __shfl_xor(s, i);
    __shared__ float ss[4];
    if ((tid & 63) == 0) ss[tid >> 6] = s;
    __syncthreads();
    if (tid == 0) {
        float t = (ss[0] + ss[1]) + (ss[2] + ss[3]);
        inv[row] = 1.0f / t;
    }
}

// ---------------------------------------------------------------------------
extern "C" void kernel_launch(void* const* d_in, const int* in_sizes, int n_in,
                              void* d_out, int out_size, void* d_ws, size_t ws_size,
                              hipStream_t stream) {
    const float* x  = (const float*)d_in[0];
    const void*  mask = d_in[1];
    const float* qw = (const float*)d_in[2];
    const float* kw = (const float*)d_in[3];
    const float* vw = (const float*)d_in[4];
    float* out = (float*)d_out;

    constexpr int B = 4, S = 2048, D = 1024;
    constexpr long BS  = (long)B * S;      // 8192
    constexpr long BSD = BS * D;           // 8388608

    char* w = (char*)d_ws;
    auto alloc = [&](size_t bytes) {
        char* p = w;
        w += (bytes + 255) & ~(size_t)255;
        return p;
    };
    float*          keep    = (float*)alloc(BS * 4);
    float*          invsum  = (float*)alloc(BS * 4);
    unsigned short* xb      = (unsigned short*)alloc((size_t)BSD * 2);
    unsigned short* wT      = (unsigned short*)alloc((size_t)3 * D * D * 2);
    unsigned short* qk      = (unsigned short*)alloc((size_t)2 * BSD * 2);  // Q,K slabs
    unsigned short* Qb = qk;
    unsigned short* Kb = qk + BSD;
    unsigned short* Vt      = (unsigned short*)alloc((size_t)BSD * 2);      // V transposed [b][d][s]

    size_t base_used = (size_t)(w - (char*)d_ws);
    size_t pB = (size_t)B * S * S * 2;  // 32 MiB unnormalized P (bf16)
    bool batched = ws_size >= base_used + pB + 1024;

    unsigned short* P;
    if (batched) {
        P = (unsigned short*)alloc(pB);
    } else {
        P = (unsigned short*)alloc((size_t)S * S * 2);
    }

    const float scale = 0.03125f;  // 1/sqrt(1024), exact

    // one prep launch: convert (8192 blocks) + transpose_w (3072) + mask (32)
    prep_kernel<<<11296, 256, 0, stream>>>(x, xb, qw, kw, vw, wT,
                                           (const unsigned char*)mask, keep, (int)BS);

    // Q,K,V projections: depth-2 ring, 3 blocks/CU -> 768 blocks = one round
    gemm8_qkv<<<dim3(64, 4, 3), 512, 0, stream>>>(xb, wT, qk, Vt,
                                                  1024, 1024, 1024, 1024,
                                                  0L, (long)D * D, BSD);

    if (batched) {
        // P = exp(QK^T * scale * keep), bf16  (512 blocks = one 2/CU round)
        gemm8_scores<<<dim3(16, 8, B), 512, 0, stream>>>(Qb, Kb, P, keep,
                                                         1024, 1024, 1024, 2048,
                                                         (long)S * D, (long)S * D, (long)S * S, (long)S, scale);
        rowsum_inv<<<(int)BS, 256, 0, stream>>>(P, invsum, 2048);
        // out = (P * invsum[row]) . V   (8-wave depth-3 ring, 256 blocks)
        gemm8_pv<<<dim3(16, 4, B), 512, 0, stream>>>(P, Vt, out, invsum,
                                                     2048, 2048, 2048, 1024,
                                                     (long)S * S, (long)D * S, (long)S * D, (long)S);
    } else {
        for (int b = 0; b < B; b++) {
            gemm8_scores<<<dim3(16, 8, 1), 512, 0, stream>>>(Qb + (long)b * S * D, Kb + (long)b * S * D,
                                                             P, keep + (long)b * S,
                                                             1024, 1024, 1024, 2048,
                                                             0L, 0L, 0L, 0L, scale);
            rowsum_inv<<<S, 256, 0, stream>>>(P, invsum + (long)b * S, 2048);
            gemm8_pv<<<dim3(16, 4, 1), 512, 0, stream>>>(P, Vt + (long)b * D * S, out + (long)b * S * D,
                                                         invsum + (long)b * S,
                                                         2048, 2048, 2048, 1024,
                                                         0L, 0L, 0L, 0L);
        }
    }
}

// Round 19
// 169.851 us; speedup vs baseline: 3.4212x; 3.4212x over previous
//
#include <hip/hip_runtime.h>
#include <hip/hip_bf16.h>

typedef __attribute__((ext_vector_type(8))) short short8;
typedef __attribute__((ext_vector_type(4))) float floatx4;

struct ushort4v { unsigned short x, y, z, w; };

static __device__ __forceinline__ unsigned short f2bf(float f) {
    __hip_bfloat16 h = __float2bfloat16(f);
    return *reinterpret_cast<unsigned short*>(&h);
}

static __device__ __forceinline__ float bf2f(unsigned short u) {
    unsigned int v = ((unsigned int)u) << 16;
    return *reinterpret_cast<float*>(&v);
}

#define ASYNC_COPY16(gsrc, ldst)                                                            \
    __builtin_amdgcn_global_load_lds((const __attribute__((address_space(1))) void*)(gsrc), \
                                     (__attribute__((address_space(3))) void*)(ldst), 16, 0, 0)

static __device__ __forceinline__ void block_barrier() {
    asm volatile("" ::: "memory");
    __builtin_amdgcn_s_barrier();
    asm volatile("" ::: "memory");
}

// ---------------------------------------------------------------------------
// One prep launch, grid-partitioned into 3 independent jobs:
//   blocks [0,8192)        : fp32 -> bf16 convert of x (1KB per block)
//   blocks [8192,11264)    : weight transpose+convert (32x32 tile each)
//   blocks [11264,11296)   : mask expand (encoding re-derived per block)
// ---------------------------------------------------------------------------
__global__ __launch_bounds__(256) void prep_kernel(const float* __restrict__ x,
                                                   unsigned short* __restrict__ xb,
                                                   const float* __restrict__ w0,
                                                   const float* __restrict__ w1,
                                                   const float* __restrict__ w2,
                                                   unsigned short* __restrict__ wT,
                                                   const unsigned char* __restrict__ mask,
                                                   float* __restrict__ keep, int nMask) {
    __shared__ float t[32][33];
    __shared__ int s_or;
    const int b = blockIdx.x;
    const int tid = threadIdx.x;

    if (b < 8192) {                       // convert: 1024 fp32 per block
        long i = (long)b * 256 + tid;
        float4 v = ((const float4*)x)[i];
        ushort4v o;
        o.x = f2bf(v.x); o.y = f2bf(v.y); o.z = f2bf(v.z); o.w = f2bf(v.w);
        ((ushort4v*)xb)[i] = o;
    } else if (b < 11264) {               // transpose_w: 32x32 tile
        int idx = b - 8192;
        int z = idx >> 10, rem = idx & 1023;
        int bx = rem & 31, by = rem >> 5;
        const float* w = z == 0 ? w0 : (z == 1 ? w1 : w2);
        unsigned short* o = wT + (long)z * 1024 * 1024;
        int c0 = bx * 32, r0 = by * 32;
        int tx = tid & 31, ty = tid >> 5;  // 32 x 8
        for (int i = ty; i < 32; i += 8)
            t[i][tx] = w[(long)(r0 + i) * 1024 + c0 + tx];
        __syncthreads();
        for (int i = ty; i < 32; i += 8)
            o[(long)(c0 + i) * 1024 + r0 + tx] = f2bf(t[tx][i]);
    } else {                              // mask expand
        if (tid == 0) s_or = 0;
        __syncthreads();
        int acc = 0;
        for (int i = tid; i < 8192; i += 256)
            if (i & 3) acc |= mask[i];
        atomicOr(&s_or, acc);
        __syncthreads();
        const bool u8enc = (s_or != 0);
        int i = (b - 11264) * 256 + tid;
        if (i < nMask) {
            bool on = u8enc ? (mask[i] != 0) : (((const int*)mask)[i] != 0);
            keep[i] = on ? 1.0f : 0.0f;
        }
    }
}

// ---------------------------------------------------------------------------
// Ring GEMM: C[M,N] = A[M,K] * BT[N,K]^T  (bf16 in, fp32 accum)
// 128x256 tile, BK=32, 8 waves, one barrier per K-step, 64B-row swizzle.
// DEPTH=3: 72KB ring, counted vmcnt(3)/(0), 2 blocks/CU (scores, PV).
// DEPTH=2: 48KB ring, vmcnt(0)/step (loads issued a full step earlier),
//          3 blocks/CU by LDS -> QKV's 768-block grid = exactly one round.
// NOTE: launch_bounds min-waves stays at 4 — round-15 showed (512,6) caps
// VGPR at 40 and spills the 64-VGPR accumulator to scratch (2.3GB/dispatch).
// EPI 0: QKV — z<2 bf16 C; z==2 V TRANSPOSED to vt via LDS (two 128-d-half
//        passes to fit the 48KB ring; batch-decomposed flattened M).
// EPI 1: bf16 exp(acc*scale*keep[row]).   EPI 2: fp32 acc*invsum[row].
// ---------------------------------------------------------------------------
template <int EPI, int DEPTH>
static __device__ __forceinline__ void gemm8_body(const unsigned short* __restrict__ A,
                                                  const unsigned short* __restrict__ B,
                                                  void* __restrict__ Cv,
                                                  unsigned short* __restrict__ vt,
                                                  const float* __restrict__ aux,
                                                  int K, int lda, int ldb, int ldc,
                                                  long sA, long sB, long sC, long sAux,
                                                  float scale) {
    constexpr int TILE = (128 + 256) * 32 * 2;  // 24576 B per K-tile (A+B)
    __shared__ char sm[DEPTH * TILE];

    const int tid = threadIdx.x;
    const int wid = tid >> 6, lane = tid & 63;
    const int wm  = wid >> 2, wn = wid & 3;       // 2 x 4 wave grid
    const int fr  = lane & 15, fk = lane >> 4;
    const long m0 = (long)blockIdx.x * 128;
    const long n0 = (long)blockIdx.y * 256;
    const unsigned short* Ab = A + (long)blockIdx.z * sA + m0 * lda;
    const unsigned short* Bb = B + (long)blockIdx.z * sB + n0 * ldb;
    const int NT = K >> 5;

    floatx4 acc[4][4] = {};

    auto stage = [&](int kt, int buf) {
        char* dA = sm + buf * TILE;
        char* dB = dA + 128 * 64;                 // A part = 8192 B
        const int kb = kt << 5;
        {
            int lam = tid * 16;
            int lg  = lam ^ (((lam >> 7) & 3) << 4);
            ASYNC_COPY16(Ab + (long)(lg >> 6) * lda + kb + ((lg & 63) >> 1), dA + lam);
        }
#pragma unroll
        for (int i = 0; i < 2; i++) {
            int lam = i * 8192 + tid * 16;
            int lg  = lam ^ (((lam >> 7) & 3) << 4);
            ASYNC_COPY16(Bb + (long)(lg >> 6) * ldb + kb + ((lg & 63) >> 1), dB + lam);
        }
    };

    stage(0, 0);
    if (DEPTH == 3) stage(1, 1);

    int cur = 0;
    for (int t = 0; t < NT; t++) {
        if (DEPTH == 3) {
            if (t + 1 < NT) asm volatile("s_waitcnt vmcnt(3)" ::: "memory");
            else            asm volatile("s_waitcnt vmcnt(0)" ::: "memory");
        } else {
            asm volatile("s_waitcnt vmcnt(0)" ::: "memory");
        }
        block_barrier();   // all waves' reads of tile t-1 returned (lgkm chain)

        const char* bA = sm + cur * TILE;
        const char* bB = bA + 128 * 64;
        short8 af[4], bf[4];
#pragma unroll
        for (int mi = 0; mi < 4; mi++) {
            int row = wm * 64 + mi * 16 + fr;
            int c   = (fk * 16) ^ (((row >> 1) & 3) << 4);
            af[mi] = *(const short8*)(bA + row * 64 + c);
        }
#pragma unroll
        for (int ni = 0; ni < 4; ni++) {
            int row = wn * 64 + ni * 16 + fr;
            int c   = (fk * 16) ^ (((row >> 1) & 3) << 4);
            bf[ni] = *(const short8*)(bB + row * 64 + c);
        }
        if (DEPTH == 3) {
            if (t + 2 < NT) stage(t + 2, (cur + 2) % 3);
        } else {
            if (t + 1 < NT) stage(t + 1, cur ^ 1);
        }

        __builtin_amdgcn_s_setprio(1);
#pragma unroll
        for (int mi = 0; mi < 4; mi++)
#pragma unroll
            for (int ni = 0; ni < 4; ni++)
                acc[mi][ni] = __builtin_amdgcn_mfma_f32_16x16x32_bf16(af[mi], bf[ni], acc[mi][ni], 0, 0, 0);
        __builtin_amdgcn_s_setprio(0);
        cur = (DEPTH == 3) ? ((cur == 2) ? 0 : cur + 1) : (cur ^ 1);
    }

    const int crow = (lane >> 4) * 4;
    const int ccol = lane & 15;

    if (EPI == 0 && blockIdx.z == 2) {
        // V: emit TRANSPOSED via LDS in two 128-d-half passes (fits 48KB ring).
        unsigned short* T = (unsigned short*)sm;
        constexpr int LDT = 132;                 // pad breaks bank conflicts
        const long bb   = m0 >> 11;              // batch = m0 / 2048
        const long sloc = m0 & 2047;             // s offset within batch
        unsigned short* vb = vt + bb * (1024L * 2048) + sloc;
#pragma unroll
        for (int dh = 0; dh < 2; dh++) {
            block_barrier();                     // ring reads / prior pass done
            if ((wn >> 1) == dh) {               // waves owning this d-half
#pragma unroll
                for (int mi = 0; mi < 4; mi++)
#pragma unroll
                    for (int j = 0; j < 4; j++) {
                        int rl = wm * 64 + mi * 16 + crow + j;        // s-local
#pragma unroll
                        for (int ni = 0; ni < 4; ni++) {
                            int clh = (wn & 1) * 64 + ni * 16 + ccol; // d within half
                            T[clh * LDT + rl] = f2bf(acc[mi][ni][j]);
                        }
                    }
            }
            block_barrier();
            // store this 128-d x 128-s half: 2048 chunks of 16B over 512 thr
#pragma unroll
            for (int p = 0; p < 4; p++) {
                int chunk = p * 512 + tid;
                int d  = chunk >> 4;
                int s0 = (chunk & 15) * 8;
                short8 v = *(const short8*)&T[d * LDT + s0];
                *(short8*)(vb + (n0 + dh * 128 + d) * 2048 + s0) = v;
            }
        }
        return;
    }

#pragma unroll
    for (int mi = 0; mi < 4; mi++) {
#pragma unroll
        for (int j = 0; j < 4; j++) {
            long r = m0 + wm * 64 + mi * 16 + crow + j;
            float rowf = 0.0f;
            if (EPI == 1) rowf = scale * aux[(long)blockIdx.z * sAux + r];  // scale*keep
            if (EPI == 2) rowf = aux[(long)blockIdx.z * sAux + r];          // invsum
#pragma unroll
            for (int ni = 0; ni < 4; ni++) {
                long c = n0 + wn * 64 + ni * 16 + ccol;
                float v = acc[mi][ni][j];
                if (EPI == 0) {
                    ((unsigned short*)Cv)[(long)blockIdx.z * sC + r * ldc + c] = f2bf(v);
                } else if (EPI == 1) {
                    ((unsigned short*)Cv)[(long)blockIdx.z * sC + r * ldc + c] = f2bf(__expf(v * rowf));
                } else {
                    ((float*)Cv)[(long)blockIdx.z * sC + r * ldc + c] = v * rowf;
                }
            }
        }
    }
}

__global__ __launch_bounds__(512, 4) void gemm8_qkv(const unsigned short* __restrict__ A,
                                                    const unsigned short* __restrict__ B,
                                                    void* __restrict__ Cv,
                                                    unsigned short* __restrict__ vt,
                                                    int K, int lda, int ldb, int ldc,
                                                    long sA, long sB, long sC) {
    gemm8_body<0, 2>(A, B, Cv, vt, nullptr, K, lda, ldb, ldc, sA, sB, sC, 0L, 1.0f);
}

__global__ __launch_bounds__(512, 4) void gemm8_scores(const unsigned short* __restrict__ A,
                                                       const unsigned short* __restrict__ B,
                                                       void* __restrict__ Cv,
                                                       const float* __restrict__ keep,
                                                       int K, int lda, int ldb, int ldc,
                                                       long sA, long sB, long sC, long sAux,
                                                       float scale) {
    gemm8_body<1, 3>(A, B, Cv, nullptr, keep, K, lda, ldb, ldc, sA, sB, sC, sAux, scale);
}

__global__ __launch_bounds__(512, 4) void gemm8_pv(const unsigned short* __restrict__ A,
                                                   const unsigned short* __restrict__ B,
                                                   void* __restrict__ Cv,
                                                   const float* __restrict__ invsum,
                                                   int K, int lda, int ldb, int ldc,
                                                   long sA, long sB, long sC, long sAux) {
    gemm8_body<2, 3>(A, B, Cv, nullptr, invsum, K, lda, ldb, ldc, sA, sB, sC, sAux, 1.0f);
}

// ---------------------------------------------------------------------------
__global__ __launch_bounds__(256) void rowsum_inv(const unsigned short* __restrict__ P,
                                                  float* __restrict__ inv, long strideP) {
    const int tid = threadIdx.x;
    const long row = blockIdx.x;
    short8 v = ((const short8*)(P + row * strideP))[tid];
    float s = 0.0f;
#pragma unroll
    for (int i = 0; i < 8; i++) s += bf2f((unsigned short)v[i]);
#pragma unroll
    for (int i = 1; i < 64; i <<= 1) s += __shfl_xor(s, i);
    __shared__ float ss[4];
    if ((tid & 63) == 0) ss[tid >> 6] = s;
    __syncthreads();
    if (tid == 0) {
        float t = (ss[0] + ss[1]) + (ss[2] + ss[3]);
        inv[row] = 1.0f / t;
    }
}

// ---------------------------------------------------------------------------
extern "C" void kernel_launch(void* const* d_in, const int* in_sizes, int n_in,
                              void* d_out, int out_size, void* d_ws, size_t ws_size,
                              hipStream_t stream) {
    const float* x  = (const float*)d_in[0];
    const void*  mask = d_in[1];
    const float* qw = (const float*)d_in[2];
    const float* kw = (const float*)d_in[3];
    const float* vw = (const float*)d_in[4];
    float* out = (float*)d_out;

    constexpr int B = 4, S = 2048, D = 1024;
    constexpr long BS  = (long)B * S;      // 8192
    constexpr long BSD = BS * D;           // 8388608

    char* w = (char*)d_ws;
    auto alloc = [&](size_t bytes) {
        char* p = w;
        w += (bytes + 255) & ~(size_t)255;
        return p;
    };
    float*          keep    = (float*)alloc(BS * 4);
    float*          invsum  = (float*)alloc(BS * 4);
    unsigned short* xb      = (unsigned short*)alloc((size_t)BSD * 2);
    unsigned short* wT      = (unsigned short*)alloc((size_t)3 * D * D * 2);
    unsigned short* qk      = (unsigned short*)alloc((size_t)2 * BSD * 2);  // Q,K slabs
    unsigned short* Qb = qk;
    unsigned short* Kb = qk + BSD;
    unsigned short* Vt      = (unsigned short*)alloc((size_t)BSD * 2);      // V transposed [b][d][s]

    size_t base_used = (size_t)(w - (char*)d_ws);
    size_t pB = (size_t)B * S * S * 2;  // 32 MiB unnormalized P (bf16)
    bool batched = ws_size >= base_used + pB + 1024;

    unsigned short* P;
    if (batched) {
        P = (unsigned short*)alloc(pB);
    } else {
        P = (unsigned short*)alloc((size_t)S * S * 2);
    }

    const float scale = 0.03125f;  // 1/sqrt(1024), exact

    // one prep launch: convert (8192 blocks) + transpose_w (3072) + mask (32)
    prep_kernel<<<11296, 256, 0, stream>>>(x, xb, qw, kw, vw, wT,
                                           (const unsigned char*)mask, keep, (int)BS);

    // Q,K,V projections: depth-2 ring, 3 blocks/CU by LDS -> 768 = one round
    gemm8_qkv<<<dim3(64, 4, 3), 512, 0, stream>>>(xb, wT, qk, Vt,
                                                  1024, 1024, 1024, 1024,
                                                  0L, (long)D * D, BSD);

    if (batched) {
        // P = exp(QK^T * scale * keep), bf16  (512 blocks = one 2/CU round)
        gemm8_scores<<<dim3(16, 8, B), 512, 0, stream>>>(Qb, Kb, P, keep,
                                                         1024, 1024, 1024, 2048,
                                                         (long)S * D, (long)S * D, (long)S * S, (long)S, scale);
        rowsum_inv<<<(int)BS, 256, 0, stream>>>(P, invsum, 2048);
        // out = (P * invsum[row]) . V   (8-wave depth-3 ring, 256 blocks)
        gemm8_pv<<<dim3(16, 4, B), 512, 0, stream>>>(P, Vt, out, invsum,
                                                     2048, 2048, 2048, 1024,
                                                     (long)S * S, (long)D * S, (long)S * D, (long)S);
    } else {
        for (int b = 0; b < B; b++) {
            gemm8_scores<<<dim3(16, 8, 1), 512, 0, stream>>>(Qb + (long)b * S * D, Kb + (long)b * S * D,
                                                             P, keep + (long)b * S,
                                                             1024, 1024, 1024, 2048,
                                                             0L, 0L, 0L, 0L, scale);
            rowsum_inv<<<S, 256, 0, stream>>>(P, invsum + (long)b * S, 2048);
            gemm8_pv<<<dim3(16, 4, 1), 512, 0, stream>>>(P, Vt + (long)b * D * S, out + (long)b * S * D,
                                                         invsum + (long)b * S,
                                                         2048, 2048, 2048, 1024,
                                                         0L, 0L, 0L, 0L);
        }
    }
}

// Round 20
// 166.614 us; speedup vs baseline: 3.4877x; 1.0194x over previous
//
#include <hip/hip_runtime.h>
#include <hip/hip_bf16.h>

typedef __attribute__((ext_vector_type(8))) short short8;
typedef __attribute__((ext_vector_type(4))) float floatx4;

struct ushort4v { unsigned short x, y, z, w; };

static __device__ __forceinline__ unsigned short f2bf(float f) {
    __hip_bfloat16 h = __float2bfloat16(f);
    return *reinterpret_cast<unsigned short*>(&h);
}

static __device__ __forceinline__ float bf2f(unsigned short u) {
    unsigned int v = ((unsigned int)u) << 16;
    return *reinterpret_cast<float*>(&v);
}

#define ASYNC_COPY16(gsrc, ldst)                                                            \
    __builtin_amdgcn_global_load_lds((const __attribute__((address_space(1))) void*)(gsrc), \
                                     (__attribute__((address_space(3))) void*)(ldst), 16, 0, 0)

static __device__ __forceinline__ void block_barrier() {
    asm volatile("" ::: "memory");
    __builtin_amdgcn_s_barrier();
    asm volatile("" ::: "memory");
}

// ---------------------------------------------------------------------------
// One prep launch, grid-partitioned into 3 independent jobs (measured +5us
// vs three separate launches):
//   blocks [0,8192)        : fp32 -> bf16 convert of x (1KB per block)
//   blocks [8192,11264)    : weight transpose+convert (32x32 tile each)
//   blocks [11264,11296)   : mask expand (encoding re-derived per block)
// ---------------------------------------------------------------------------
__global__ __launch_bounds__(256) void prep_kernel(const float* __restrict__ x,
                                                   unsigned short* __restrict__ xb,
                                                   const float* __restrict__ w0,
                                                   const float* __restrict__ w1,
                                                   const float* __restrict__ w2,
                                                   unsigned short* __restrict__ wT,
                                                   const unsigned char* __restrict__ mask,
                                                   float* __restrict__ keep, int nMask) {
    __shared__ float t[32][33];
    __shared__ int s_or;
    const int b = blockIdx.x;
    const int tid = threadIdx.x;

    if (b < 8192) {                       // convert: 1024 fp32 per block
        long i = (long)b * 256 + tid;
        float4 v = ((const float4*)x)[i];
        ushort4v o;
        o.x = f2bf(v.x); o.y = f2bf(v.y); o.z = f2bf(v.z); o.w = f2bf(v.w);
        ((ushort4v*)xb)[i] = o;
    } else if (b < 11264) {               // transpose_w: 32x32 tile
        int idx = b - 8192;
        int z = idx >> 10, rem = idx & 1023;
        int bx = rem & 31, by = rem >> 5;
        const float* w = z == 0 ? w0 : (z == 1 ? w1 : w2);
        unsigned short* o = wT + (long)z * 1024 * 1024;
        int c0 = bx * 32, r0 = by * 32;
        int tx = tid & 31, ty = tid >> 5;  // 32 x 8
        for (int i = ty; i < 32; i += 8)
            t[i][tx] = w[(long)(r0 + i) * 1024 + c0 + tx];
        __syncthreads();
        for (int i = ty; i < 32; i += 8)
            o[(long)(c0 + i) * 1024 + r0 + tx] = f2bf(t[tx][i]);
    } else {                              // mask expand
        if (tid == 0) s_or = 0;
        __syncthreads();
        int acc = 0;
        for (int i = tid; i < 8192; i += 256)
            if (i & 3) acc |= mask[i];
        atomicOr(&s_or, acc);
        __syncthreads();
        const bool u8enc = (s_or != 0);
        int i = (b - 11264) * 256 + tid;
        if (i < nMask) {
            bool on = u8enc ? (mask[i] != 0) : (((const int*)mask)[i] != 0);
            keep[i] = on ? 1.0f : 0.0f;
        }
    }
}

// ---------------------------------------------------------------------------
// Ring GEMM (measured-best config): C[M,N] = A[M,K] * BT[N,K]^T, bf16/fp32.
// 128x256 tile, BK=32, 8 waves, depth-3 LDS ring (72KB -> 2 blocks/CU),
// ONE barrier per K-step, counted vmcnt(3)/(0), 64B-row swizzle both sides.
// A/B history: depth-2 QKV (3 blocks/CU capacity) measured SLOWER (62.6 vs
// 58.5 us) — per-step vmcnt(0) drain beats the extra block. Keep depth-3.
// launch_bounds min-waves 4: (512,6) caps VGPR at 40 -> accumulator spills.
// EPI 0: QKV — z<2 bf16 C; z==2 V TRANSPOSED to vt via LDS single pass
//        (T[256][132] = 67.6KB fits the 72KB ring; batch-decomposed M).
// EPI 1: bf16 exp(acc*scale*keep[row]).   EPI 2: fp32 acc*invsum[row].
// ---------------------------------------------------------------------------
template <int EPI>
static __device__ __forceinline__ void gemm8_body(const unsigned short* __restrict__ A,
                                                  const unsigned short* __restrict__ B,
                                                  void* __restrict__ Cv,
                                                  unsigned short* __restrict__ vt,
                                                  const float* __restrict__ aux,
                                                  int K, int lda, int ldb, int ldc,
                                                  long sA, long sB, long sC, long sAux,
                                                  float scale) {
    constexpr int TILE = (128 + 256) * 32 * 2;  // 24576 B per K-tile (A+B)
    __shared__ char sm[3 * TILE];

    const int tid = threadIdx.x;
    const int wid = tid >> 6, lane = tid & 63;
    const int wm  = wid >> 2, wn = wid & 3;       // 2 x 4 wave grid
    const int fr  = lane & 15, fk = lane >> 4;
    const long m0 = (long)blockIdx.x * 128;
    const long n0 = (long)blockIdx.y * 256;
    const unsigned short* Ab = A + (long)blockIdx.z * sA + m0 * lda;
    const unsigned short* Bb = B + (long)blockIdx.z * sB + n0 * ldb;
    const int NT = K >> 5;

    floatx4 acc[4][4] = {};

    auto stage = [&](int kt, int buf) {
        char* dA = sm + buf * TILE;
        char* dB = dA + 128 * 64;                 // A part = 8192 B
        const int kb = kt << 5;
        {
            int lam = tid * 16;
            int lg  = lam ^ (((lam >> 7) & 3) << 4);
            ASYNC_COPY16(Ab + (long)(lg >> 6) * lda + kb + ((lg & 63) >> 1), dA + lam);
        }
#pragma unroll
        for (int i = 0; i < 2; i++) {
            int lam = i * 8192 + tid * 16;
            int lg  = lam ^ (((lam >> 7) & 3) << 4);
            ASYNC_COPY16(Bb + (long)(lg >> 6) * ldb + kb + ((lg & 63) >> 1), dB + lam);
        }
    };

    stage(0, 0);
    stage(1, 1);

    int cur = 0;
    for (int t = 0; t < NT; t++) {
        if (t + 1 < NT) asm volatile("s_waitcnt vmcnt(3)" ::: "memory");
        else            asm volatile("s_waitcnt vmcnt(0)" ::: "memory");
        block_barrier();   // all waves' reads of tile t-1 returned (lgkm chain)

        const char* bA = sm + cur * TILE;
        const char* bB = bA + 128 * 64;
        short8 af[4], bf[4];
#pragma unroll
        for (int mi = 0; mi < 4; mi++) {
            int row = wm * 64 + mi * 16 + fr;
            int c   = (fk * 16) ^ (((row >> 1) & 3) << 4);
            af[mi] = *(const short8*)(bA + row * 64 + c);
        }
#pragma unroll
        for (int ni = 0; ni < 4; ni++) {
            int row = wn * 64 + ni * 16 + fr;
            int c   = (fk * 16) ^ (((row >> 1) & 3) << 4);
            bf[ni] = *(const short8*)(bB + row * 64 + c);
        }
        if (t + 2 < NT) stage(t + 2, (cur + 2) % 3);   // refill buf freed at this barrier

        __builtin_amdgcn_s_setprio(1);
#pragma unroll
        for (int mi = 0; mi < 4; mi++)
#pragma unroll
            for (int ni = 0; ni < 4; ni++)
                acc[mi][ni] = __builtin_amdgcn_mfma_f32_16x16x32_bf16(af[mi], bf[ni], acc[mi][ni], 0, 0, 0);
        __builtin_amdgcn_s_setprio(0);
        cur = (cur == 2) ? 0 : cur + 1;
    }

    const int crow = (lane >> 4) * 4;
    const int ccol = lane & 15;

    if (EPI == 0 && blockIdx.z == 2) {
        // V projection: emit TRANSPOSED via LDS. T[256 d][132 pad] = 67.6KB.
        block_barrier();   // all waves done with ring LDS
        unsigned short* T = (unsigned short*)sm;
        constexpr int LDT = 132;
#pragma unroll
        for (int mi = 0; mi < 4; mi++)
#pragma unroll
            for (int j = 0; j < 4; j++) {
                int rl = wm * 64 + mi * 16 + crow + j;      // s-local (0..127)
#pragma unroll
                for (int ni = 0; ni < 4; ni++) {
                    int cl = wn * 64 + ni * 16 + ccol;      // d-local (0..255)
                    T[cl * LDT + rl] = f2bf(acc[mi][ni][j]);
                }
            }
        block_barrier();
        // store Vt[b][d][s]: batch-decompose the flattened M index
        const long bb   = m0 >> 11;              // batch = m0 / 2048
        const long sloc = m0 & 2047;             // s offset within batch
        unsigned short* vb = vt + bb * (1024L * 2048) + sloc;
#pragma unroll
        for (int p = 0; p < 8; p++) {
            int chunk = p * 512 + tid;            // 0..4095
            int d  = chunk >> 4;                  // 256 rows x 16 chunks of 8
            int s0 = (chunk & 15) * 8;
            short8 v = *(const short8*)&T[d * LDT + s0];
            *(short8*)(vb + (n0 + d) * 2048 + s0) = v;
        }
        return;
    }

#pragma unroll
    for (int mi = 0; mi < 4; mi++) {
#pragma unroll
        for (int j = 0; j < 4; j++) {
            long r = m0 + wm * 64 + mi * 16 + crow + j;
            float rowf = 0.0f;
            if (EPI == 1) rowf = scale * aux[(long)blockIdx.z * sAux + r];  // scale*keep
            if (EPI == 2) rowf = aux[(long)blockIdx.z * sAux + r];          // invsum
#pragma unroll
            for (int ni = 0; ni < 4; ni++) {
                long c = n0 + wn * 64 + ni * 16 + ccol;
                float v = acc[mi][ni][j];
                if (EPI == 0) {
                    ((unsigned short*)Cv)[(long)blockIdx.z * sC + r * ldc + c] = f2bf(v);
                } else if (EPI == 1) {
                    ((unsigned short*)Cv)[(long)blockIdx.z * sC + r * ldc + c] = f2bf(__expf(v * rowf));
                } else {
                    ((float*)Cv)[(long)blockIdx.z * sC + r * ldc + c] = v * rowf;
                }
            }
        }
    }
}

__global__ __launch_bounds__(512, 4) void gemm8_qkv(const unsigned short* __restrict__ A,
                                                    const unsigned short* __restrict__ B,
                                                    void* __restrict__ Cv,
                                                    unsigned short* __restrict__ vt,
                                                    int K, int lda, int ldb, int ldc,
                                                    long sA, long sB, long sC) {
    gemm8_body<0>(A, B, Cv, vt, nullptr, K, lda, ldb, ldc, sA, sB, sC, 0L, 1.0f);
}

__global__ __launch_bounds__(512, 4) void gemm8_scores(const unsigned short* __restrict__ A,
                                                       const unsigned short* __restrict__ B,
                                                       void* __restrict__ Cv,
                                                       const float* __restrict__ keep,
                                                       int K, int lda, int ldb, int ldc,
                                                       long sA, long sB, long sC, long sAux,
                                                       float scale) {
    gemm8_body<1>(A, B, Cv, nullptr, keep, K, lda, ldb, ldc, sA, sB, sC, sAux, scale);
}

__global__ __launch_bounds__(512, 4) void gemm8_pv(const unsigned short* __restrict__ A,
                                                   const unsigned short* __restrict__ B,
                                                   void* __restrict__ Cv,
                                                   const float* __restrict__ invsum,
                                                   int K, int lda, int ldb, int ldc,
                                                   long sA, long sB, long sC, long sAux) {
    gemm8_body<2>(A, B, Cv, nullptr, invsum, K, lda, ldb, ldc, sA, sB, sC, sAux, 1.0f);
}

// ---------------------------------------------------------------------------
__global__ __launch_bounds__(256) void rowsum_inv(const unsigned short* __restrict__ P,
                                                  float* __restrict__ inv, long strideP) {
    const int tid = threadIdx.x;
    const long row = blockIdx.x;
    short8 v = ((const short8*)(P + row * strideP))[tid];
    float s = 0.0f;
#pragma unroll
    for (int i = 0; i < 8; i++) s += bf2f((unsigned short)v[i]);
#pragma unroll
    for (int i = 1; i < 64; i <<= 1) s += __shfl_xor(s, i);
    __shared__ float ss[4];
    if ((tid & 63) == 0) ss[tid >> 6] = s;
    __syncthreads();
    if (tid == 0) {
        float t = (ss[0] + ss[1]) + (ss[2] + ss[3]);
        inv[row] = 1.0f / t;
    }
}

// ---------------------------------------------------------------------------
extern "C" void kernel_launch(void* const* d_in, const int* in_sizes, int n_in,
                              void* d_out, int out_size, void* d_ws, size_t ws_size,
                              hipStream_t stream) {
    const float* x  = (const float*)d_in[0];
    const void*  mask = d_in[1];
    const float* qw = (const float*)d_in[2];
    const float* kw = (const float*)d_in[3];
    const float* vw = (const float*)d_in[4];
    float* out = (float*)d_out;

    constexpr int B = 4, S = 2048, D = 1024;
    constexpr long BS  = (long)B * S;      // 8192
    constexpr long BSD = BS * D;           // 8388608

    char* w = (char*)d_ws;
    auto alloc = [&](size_t bytes) {
        char* p = w;
        w += (bytes + 255) & ~(size_t)255;
        return p;
    };
    float*          keep    = (float*)alloc(BS * 4);
    float*          invsum  = (float*)alloc(BS * 4);
    unsigned short* xb      = (unsigned short*)alloc((size_t)BSD * 2);
    unsigned short* wT      = (unsigned short*)alloc((size_t)3 * D * D * 2);
    unsigned short* qk      = (unsigned short*)alloc((size_t)2 * BSD * 2);  // Q,K slabs
    unsigned short* Qb = qk;
    unsigned short* Kb = qk + BSD;
    unsigned short* Vt      = (unsigned short*)alloc((size_t)BSD * 2);      // V transposed [b][d][s]

    size_t base_used = (size_t)(w - (char*)d_ws);
    size_t pB = (size_t)B * S * S * 2;  // 32 MiB unnormalized P (bf16)
    bool batched = ws_size >= base_used + pB + 1024;

    unsigned short* P;
    if (batched) {
        P = (unsigned short*)alloc(pB);
    } else {
        P = (unsigned short*)alloc((size_t)S * S * 2);
    }

    const float scale = 0.03125f;  // 1/sqrt(1024), exact

    // one prep launch: convert (8192 blocks) + transpose_w (3072) + mask (32)
    prep_kernel<<<11296, 256, 0, stream>>>(x, xb, qw, kw, vw, wT,
                                           (const unsigned char*)mask, keep, (int)BS);

    // Q,K,V projections: depth-3 ring (measured-best 58.5us), 768 blocks
    gemm8_qkv<<<dim3(64, 4, 3), 512, 0, stream>>>(xb, wT, qk, Vt,
                                                  1024, 1024, 1024, 1024,
                                                  0L, (long)D * D, BSD);

    if (batched) {
        // P = exp(QK^T * scale * keep), bf16  (512 blocks = one 2/CU round)
        gemm8_scores<<<dim3(16, 8, B), 512, 0, stream>>>(Qb, Kb, P, keep,
                                                         1024, 1024, 1024, 2048,
                                                         (long)S * D, (long)S * D, (long)S * S, (long)S, scale);
        rowsum_inv<<<(int)BS, 256, 0, stream>>>(P, invsum, 2048);
        // out = (P * invsum[row]) . V   (8-wave depth-3 ring, 256 blocks)
        gemm8_pv<<<dim3(16, 4, B), 512, 0, stream>>>(P, Vt, out, invsum,
                                                     2048, 2048, 2048, 1024,
                                                     (long)S * S, (long)D * S, (long)S * D, (long)S);
    } else {
        for (int b = 0; b < B; b++) {
            gemm8_scores<<<dim3(16, 8, 1), 512, 0, stream>>>(Qb + (long)b * S * D, Kb + (long)b * S * D,
                                                             P, keep + (long)b * S,
                                                             1024, 1024, 1024, 2048,
                                                             0L, 0L, 0L, 0L, scale);
            rowsum_inv<<<S, 256, 0, stream>>>(P, invsum + (long)b * S, 2048);
            gemm8_pv<<<dim3(16, 4, 1), 512, 0, stream>>>(P, Vt + (long)b * D * S, out + (long)b * S * D,
                                                         invsum + (long)b * S,
                                                         2048, 2048, 2048, 1024,
                                                         0L, 0L, 0L, 0L);
        }
    }
}

// Round 21
// 165.111 us; speedup vs baseline: 3.5194x; 1.0091x over previous
//
#include <hip/hip_runtime.h>
#include <hip/hip_bf16.h>

typedef __attribute__((ext_vector_type(8))) short short8;
typedef __attribute__((ext_vector_type(4))) float floatx4;

struct ushort4v { unsigned short x, y, z, w; };

static __device__ __forceinline__ unsigned short f2bf(float f) {
    __hip_bfloat16 h = __float2bfloat16(f);
    return *reinterpret_cast<unsigned short*>(&h);
}

static __device__ __forceinline__ float bf2f(unsigned short u) {
    unsigned int v = ((unsigned int)u) << 16;
    return *reinterpret_cast<float*>(&v);
}

#define ASYNC_COPY16(gsrc, ldst)                                                            \
    __builtin_amdgcn_global_load_lds((const __attribute__((address_space(1))) void*)(gsrc), \
                                     (__attribute__((address_space(3))) void*)(ldst), 16, 0, 0)

static __device__ __forceinline__ void block_barrier() {
    asm volatile("" ::: "memory");
    __builtin_amdgcn_s_barrier();
    asm volatile("" ::: "memory");
}

// ---------------------------------------------------------------------------
// One prep launch, grid-partitioned into 3 independent jobs (measured +5us
// vs three separate launches):
//   blocks [0,8192)        : fp32 -> bf16 convert of x (1KB per block)
//   blocks [8192,11264)    : weight transpose+convert (32x32 tile each)
//   blocks [11264,11296)   : mask expand (encoding re-derived per block)
// ---------------------------------------------------------------------------
__global__ __launch_bounds__(256) void prep_kernel(const float* __restrict__ x,
                                                   unsigned short* __restrict__ xb,
                                                   const float* __restrict__ w0,
                                                   const float* __restrict__ w1,
                                                   const float* __restrict__ w2,
                                                   unsigned short* __restrict__ wT,
                                                   const unsigned char* __restrict__ mask,
                                                   float* __restrict__ keep, int nMask) {
    __shared__ float t[32][33];
    __shared__ int s_or;
    const int b = blockIdx.x;
    const int tid = threadIdx.x;

    if (b < 8192) {                       // convert: 1024 fp32 per block
        long i = (long)b * 256 + tid;
        float4 v = ((const float4*)x)[i];
        ushort4v o;
        o.x = f2bf(v.x); o.y = f2bf(v.y); o.z = f2bf(v.z); o.w = f2bf(v.w);
        ((ushort4v*)xb)[i] = o;
    } else if (b < 11264) {               // transpose_w: 32x32 tile
        int idx = b - 8192;
        int z = idx >> 10, rem = idx & 1023;
        int bx = rem & 31, by = rem >> 5;
        const float* w = z == 0 ? w0 : (z == 1 ? w1 : w2);
        unsigned short* o = wT + (long)z * 1024 * 1024;
        int c0 = bx * 32, r0 = by * 32;
        int tx = tid & 31, ty = tid >> 5;  // 32 x 8
        for (int i = ty; i < 32; i += 8)
            t[i][tx] = w[(long)(r0 + i) * 1024 + c0 + tx];
        __syncthreads();
        for (int i = ty; i < 32; i += 8)
            o[(long)(c0 + i) * 1024 + r0 + tx] = f2bf(t[tx][i]);
    } else {                              // mask expand
        if (tid == 0) s_or = 0;
        __syncthreads();
        int acc = 0;
        for (int i = tid; i < 8192; i += 256)
            if (i & 3) acc |= mask[i];
        atomicOr(&s_or, acc);
        __syncthreads();
        const bool u8enc = (s_or != 0);
        int i = (b - 11264) * 256 + tid;
        if (i < nMask) {
            bool on = u8enc ? (mask[i] != 0) : (((const int*)mask)[i] != 0);
            keep[i] = on ? 1.0f : 0.0f;
        }
    }
}

// ---------------------------------------------------------------------------
// Ring GEMM (measured-best config): C[M,N] = A[M,K] * BT[N,K]^T, bf16/fp32.
// 128x256 tile, BK=32, 8 waves, depth-3 LDS ring (72KB -> 2 blocks/CU),
// ONE barrier per K-step, counted vmcnt(3)/(0), 64B-row swizzle both sides.
// A/B history: depth-2 QKV (3 blocks/CU capacity) measured SLOWER (62.6 vs
// 58.5 us). launch_bounds min-waves 4: (512,6) caps VGPR at 40 -> spills.
// EPI 0: QKV — z<2 bf16 C; z==2 V TRANSPOSED to vt via LDS single pass.
// EPI 1: scores — bf16 exp(acc*scale*keep[row]) + per-block row partial
//        sums (in-register + shfl + 2KB LDS) -> psum[row][by] (fp32).
// EPI 2: PV — fp32 acc*invsum[row].
// ---------------------------------------------------------------------------
template <int EPI>
static __device__ __forceinline__ void gemm8_body(const unsigned short* __restrict__ A,
                                                  const unsigned short* __restrict__ B,
                                                  void* __restrict__ Cv,
                                                  unsigned short* __restrict__ vt,
                                                  const float* __restrict__ aux,
                                                  float* __restrict__ psum,
                                                  int K, int lda, int ldb, int ldc,
                                                  long sA, long sB, long sC, long sAux,
                                                  float scale) {
    constexpr int TILE = (128 + 256) * 32 * 2;  // 24576 B per K-tile (A+B)
    __shared__ char sm[3 * TILE];

    const int tid = threadIdx.x;
    const int wid = tid >> 6, lane = tid & 63;
    const int wm  = wid >> 2, wn = wid & 3;       // 2 x 4 wave grid
    const int fr  = lane & 15, fk = lane >> 4;
    const long m0 = (long)blockIdx.x * 128;
    const long n0 = (long)blockIdx.y * 256;
    const unsigned short* Ab = A + (long)blockIdx.z * sA + m0 * lda;
    const unsigned short* Bb = B + (long)blockIdx.z * sB + n0 * ldb;
    const int NT = K >> 5;

    floatx4 acc[4][4] = {};

    auto stage = [&](int kt, int buf) {
        char* dA = sm + buf * TILE;
        char* dB = dA + 128 * 64;                 // A part = 8192 B
        const int kb = kt << 5;
        {
            int lam = tid * 16;
            int lg  = lam ^ (((lam >> 7) & 3) << 4);
            ASYNC_COPY16(Ab + (long)(lg >> 6) * lda + kb + ((lg & 63) >> 1), dA + lam);
        }
#pragma unroll
        for (int i = 0; i < 2; i++) {
            int lam = i * 8192 + tid * 16;
            int lg  = lam ^ (((lam >> 7) & 3) << 4);
            ASYNC_COPY16(Bb + (long)(lg >> 6) * ldb + kb + ((lg & 63) >> 1), dB + lam);
        }
    };

    stage(0, 0);
    stage(1, 1);

    int cur = 0;
    for (int t = 0; t < NT; t++) {
        if (t + 1 < NT) asm volatile("s_waitcnt vmcnt(3)" ::: "memory");
        else            asm volatile("s_waitcnt vmcnt(0)" ::: "memory");
        block_barrier();   // all waves' reads of tile t-1 returned (lgkm chain)

        const char* bA = sm + cur * TILE;
        const char* bB = bA + 128 * 64;
        short8 af[4], bf[4];
#pragma unroll
        for (int mi = 0; mi < 4; mi++) {
            int row = wm * 64 + mi * 16 + fr;
            int c   = (fk * 16) ^ (((row >> 1) & 3) << 4);
            af[mi] = *(const short8*)(bA + row * 64 + c);
        }
#pragma unroll
        for (int ni = 0; ni < 4; ni++) {
            int row = wn * 64 + ni * 16 + fr;
            int c   = (fk * 16) ^ (((row >> 1) & 3) << 4);
            bf[ni] = *(const short8*)(bB + row * 64 + c);
        }
        if (t + 2 < NT) stage(t + 2, (cur + 2) % 3);   // refill buf freed at this barrier

        __builtin_amdgcn_s_setprio(1);
#pragma unroll
        for (int mi = 0; mi < 4; mi++)
#pragma unroll
            for (int ni = 0; ni < 4; ni++)
                acc[mi][ni] = __builtin_amdgcn_mfma_f32_16x16x32_bf16(af[mi], bf[ni], acc[mi][ni], 0, 0, 0);
        __builtin_amdgcn_s_setprio(0);
        cur = (cur == 2) ? 0 : cur + 1;
    }

    const int crow = (lane >> 4) * 4;
    const int ccol = lane & 15;

    if (EPI == 0 && blockIdx.z == 2) {
        // V projection: emit TRANSPOSED via LDS. T[256 d][132 pad] = 67.6KB.
        block_barrier();   // all waves done with ring LDS
        unsigned short* T = (unsigned short*)sm;
        constexpr int LDT = 132;
#pragma unroll
        for (int mi = 0; mi < 4; mi++)
#pragma unroll
            for (int j = 0; j < 4; j++) {
                int rl = wm * 64 + mi * 16 + crow + j;      // s-local (0..127)
#pragma unroll
                for (int ni = 0; ni < 4; ni++) {
                    int cl = wn * 64 + ni * 16 + ccol;      // d-local (0..255)
                    T[cl * LDT + rl] = f2bf(acc[mi][ni][j]);
                }
            }
        block_barrier();
        const long bb   = m0 >> 11;              // batch = m0 / 2048
        const long sloc = m0 & 2047;             // s offset within batch
        unsigned short* vb = vt + bb * (1024L * 2048) + sloc;
#pragma unroll
        for (int p = 0; p < 8; p++) {
            int chunk = p * 512 + tid;            // 0..4095
            int d  = chunk >> 4;                  // 256 rows x 16 chunks of 8
            int s0 = (chunk & 15) * 8;
            short8 v = *(const short8*)&T[d * LDT + s0];
            *(short8*)(vb + (n0 + d) * 2048 + s0) = v;
        }
        return;
    }

    if (EPI == 1) {
        // scores: store bf16 exp AND per-block row partial sums.
        block_barrier();                         // ring LDS free for partials
        float* part = (float*)sm;                // [128][4]
#pragma unroll
        for (int mi = 0; mi < 4; mi++) {
#pragma unroll
            for (int j = 0; j < 4; j++) {
                int  rl = wm * 64 + mi * 16 + crow + j;
                long r  = m0 + rl;
                float rowf = scale * aux[(long)blockIdx.z * sAux + r];  // scale*keep
                float s = 0.0f;
#pragma unroll
                for (int ni = 0; ni < 4; ni++) {
                    long c = n0 + wn * 64 + ni * 16 + ccol;
                    float e = __expf(acc[mi][ni][j] * rowf);
                    ((unsigned short*)Cv)[(long)blockIdx.z * sC + r * ldc + c] = f2bf(e);
                    s += e;
                }
                // sum across the 16-lane column group (fixed order, deterministic)
                s += __shfl_xor(s, 1); s += __shfl_xor(s, 2);
                s += __shfl_xor(s, 4); s += __shfl_xor(s, 8);
                if ((lane & 15) == 0) part[rl * 4 + wn] = s;
            }
        }
        block_barrier();
        if (tid < 128) {
            float s = (part[tid * 4 + 0] + part[tid * 4 + 1]) +
                      (part[tid * 4 + 2] + part[tid * 4 + 3]);
            psum[((long)blockIdx.z * 2048 + m0 + tid) * 8 + blockIdx.y] = s;
        }
        return;
    }

#pragma unroll
    for (int mi = 0; mi < 4; mi++) {
#pragma unroll
        for (int j = 0; j < 4; j++) {
            long r = m0 + wm * 64 + mi * 16 + crow + j;
            float rowf = 0.0f;
            if (EPI == 2) rowf = aux[(long)blockIdx.z * sAux + r];          // invsum
#pragma unroll
            for (int ni = 0; ni < 4; ni++) {
                long c = n0 + wn * 64 + ni * 16 + ccol;
                float v = acc[mi][ni][j];
                if (EPI == 0) {
                    ((unsigned short*)Cv)[(long)blockIdx.z * sC + r * ldc + c] = f2bf(v);
                } else {
                    ((float*)Cv)[(long)blockIdx.z * sC + r * ldc + c] = v * rowf;
                }
            }
        }
    }
}

__global__ __launch_bounds__(512, 4) void gemm8_qkv(const unsigned short* __restrict__ A,
                                                    const unsigned short* __restrict__ B,
                                                    void* __restrict__ Cv,
                                                    unsigned short* __restrict__ vt,
                                                    int K, int lda, int ldb, int ldc,
                                                    long sA, long sB, long sC) {
    gemm8_body<0>(A, B, Cv, vt, nullptr, nullptr, K, lda, ldb, ldc, sA, sB, sC, 0L, 1.0f);
}

__global__ __launch_bounds__(512, 4) void gemm8_scores(const unsigned short* __restrict__ A,
                                                       const unsigned short* __restrict__ B,
                                                       void* __restrict__ Cv,
                                                       const float* __restrict__ keep,
                                                       float* __restrict__ psum,
                                                       int K, int lda, int ldb, int ldc,
                                                       long sA, long sB, long sC, long sAux,
                                                       float scale) {
    gemm8_body<1>(A, B, Cv, nullptr, keep, psum, K, lda, ldb, ldc, sA, sB, sC, sAux, scale);
}

__global__ __launch_bounds__(512, 4) void gemm8_pv(const unsigned short* __restrict__ A,
                                                   const unsigned short* __restrict__ B,
                                                   void* __restrict__ Cv,
                                                   const float* __restrict__ invsum,
                                                   int K, int lda, int ldb, int ldc,
                                                   long sA, long sB, long sC, long sAux) {
    gemm8_body<2>(A, B, Cv, nullptr, invsum, nullptr, K, lda, ldb, ldc, sA, sB, sC, sAux, 1.0f);
}

// ---------------------------------------------------------------------------
// finish: invsum[row] = 1 / sum of the 8 per-block partials (256KB read)
// ---------------------------------------------------------------------------
__global__ __launch_bounds__(256) void rowsum_finish(const float* __restrict__ ps,
                                                     float* __restrict__ inv, int nrows) {
    int r = blockIdx.x * 256 + threadIdx.x;
    if (r >= nrows) return;
    const float* p = ps + (long)r * 8;
    float s = ((p[0] + p[1]) + (p[2] + p[3])) + ((p[4] + p[5]) + (p[6] + p[7]));
    inv[r] = 1.0f / s;
}

// ---------------------------------------------------------------------------
extern "C" void kernel_launch(void* const* d_in, const int* in_sizes, int n_in,
                              void* d_out, int out_size, void* d_ws, size_t ws_size,
                              hipStream_t stream) {
    const float* x  = (const float*)d_in[0];
    const void*  mask = d_in[1];
    const float* qw = (const float*)d_in[2];
    const float* kw = (const float*)d_in[3];
    const float* vw = (const float*)d_in[4];
    float* out = (float*)d_out;

    constexpr int B = 4, S = 2048, D = 1024;
    constexpr long BS  = (long)B * S;      // 8192
    constexpr long BSD = BS * D;           // 8388608

    char* w = (char*)d_ws;
    auto alloc = [&](size_t bytes) {
        char* p = w;
        w += (bytes + 255) & ~(size_t)255;
        return p;
    };
    float*          keep    = (float*)alloc(BS * 4);
    float*          invsum  = (float*)alloc(BS * 4);
    float*          psum    = (float*)alloc(BS * 8 * 4);                    // 256KB partials
    unsigned short* xb      = (unsigned short*)alloc((size_t)BSD * 2);
    unsigned short* wT      = (unsigned short*)alloc((size_t)3 * D * D * 2);
    unsigned short* qk      = (unsigned short*)alloc((size_t)2 * BSD * 2);  // Q,K slabs
    unsigned short* Qb = qk;
    unsigned short* Kb = qk + BSD;
    unsigned short* Vt      = (unsigned short*)alloc((size_t)BSD * 2);      // V transposed [b][d][s]

    size_t base_used = (size_t)(w - (char*)d_ws);
    size_t pB = (size_t)B * S * S * 2;  // 32 MiB unnormalized P (bf16)
    bool batched = ws_size >= base_used + pB + 1024;

    unsigned short* P;
    if (batched) {
        P = (unsigned short*)alloc(pB);
    } else {
        P = (unsigned short*)alloc((size_t)S * S * 2);
    }

    const float scale = 0.03125f;  // 1/sqrt(1024), exact

    // one prep launch: convert (8192 blocks) + transpose_w (3072) + mask (32)
    prep_kernel<<<11296, 256, 0, stream>>>(x, xb, qw, kw, vw, wT,
                                           (const unsigned char*)mask, keep, (int)BS);

    // Q,K,V projections: depth-3 ring (measured-best 58.5us), 768 blocks
    gemm8_qkv<<<dim3(64, 4, 3), 512, 0, stream>>>(xb, wT, qk, Vt,
                                                  1024, 1024, 1024, 1024,
                                                  0L, (long)D * D, BSD);

    if (batched) {
        // P = exp(QK^T * scale * keep), bf16 + per-block row partial sums
        gemm8_scores<<<dim3(16, 8, B), 512, 0, stream>>>(Qb, Kb, P, keep, psum,
                                                         1024, 1024, 1024, 2048,
                                                         (long)S * D, (long)S * D, (long)S * S, (long)S, scale);
        rowsum_finish<<<32, 256, 0, stream>>>(psum, invsum, (int)BS);
        // out = (P * invsum[row]) . V   (8-wave depth-3 ring, 256 blocks)
        gemm8_pv<<<dim3(16, 4, B), 512, 0, stream>>>(P, Vt, out, invsum,
                                                     2048, 2048, 2048, 1024,
                                                     (long)S * S, (long)D * S, (long)S * D, (long)S);
    } else {
        for (int b = 0; b < B; b++) {
            gemm8_scores<<<dim3(16, 8, 1), 512, 0, stream>>>(Qb + (long)b * S * D, Kb + (long)b * S * D,
                                                             P, keep + (long)b * S, psum + (long)b * S * 8,
                                                             1024, 1024, 1024, 2048,
                                                             0L, 0L, 0L, 0L, scale);
            rowsum_finish<<<8, 256, 0, stream>>>(psum + (long)b * S * 8, invsum + (long)b * S, S);
            gemm8_pv<<<dim3(16, 4, 1), 512, 0, stream>>>(P, Vt + (long)b * D * S, out + (long)b * S * D,
                                                         invsum + (long)b * S,
                                                         2048, 2048, 2048, 1024,
                                                         0L, 0L, 0L, 0L);
        }
    }
}